// Round 1
// baseline (1115.743 us; speedup 1.0000x reference)
//
#include <hip/hip_runtime.h>

#define DEV __device__ __forceinline__

typedef __bf16 bf16x8 __attribute__((ext_vector_type(8)));
typedef float  f32x4  __attribute__((ext_vector_type(4)));

// ---------- helpers ----------
DEV unsigned short f2b(float f) {                 // f32 -> bf16 (RNE)
    union { float f; unsigned u; } v; v.f = f;
    unsigned r = v.u + 0x7fffu + ((v.u >> 16) & 1u);
    return (unsigned short)(r >> 16);
}
DEV float b2f(unsigned short h) {
    union { unsigned u; float f; } v; v.u = ((unsigned)h) << 16;
    return v.f;
}
DEV float sigmoidf_(float x) { return 1.f / (1.f + __expf(-x)); }
DEV float geluf_(float x) {                       // jax default: tanh approximation
    float t = 0.7978845608028654f * (x + 0.044715f * x * x * x);
    return 0.5f * x * (1.f + tanhf(t));
}
DEV void gload_lds16(const void* g, void* l) {
    __builtin_amdgcn_global_load_lds((const __attribute__((address_space(1))) void*)g,
                                     (__attribute__((address_space(3))) void*)l, 16, 0, 0);
}

// ---------- problem constants ----------
// B=32 L=256 D=512 D_INNER=1024 D_STATE=16 DT_RANK=32 D_FF=2048, M = B*L = 8192

// ---------- weight transpose+convert: W (K,N) f32 -> W^T (N,K) bf16 ----------
struct WtDesc { const float* s; unsigned short* d; int K; int N; int t0; };
struct WtArgs { WtDesc m[8]; };

__global__ __launch_bounds__(256) void wtrans_k(WtArgs a) {
    __shared__ float tile[32][33];
    int t = blockIdx.x;
    int mi = 0;
#pragma unroll
    for (int j = 1; j < 8; j++) if (t >= a.m[j].t0) mi = j;
    const float* src0 = a.m[mi].s;
    unsigned short* dst0 = a.m[mi].d;
    const int K = a.m[mi].K, N = a.m[mi].N;
    const int lt = t - a.m[mi].t0;
    const int ntk = K >> 5;
    const int kt = lt % ntk, nt = lt / ntk;
    const int c = threadIdx.x & 31, r = threadIdx.x >> 5;
    const float* src = src0 + (size_t)(kt * 32) * N + nt * 32;
#pragma unroll
    for (int i = 0; i < 4; i++) tile[r + i * 8][c] = src[(size_t)(r + i * 8) * N + c];
    __syncthreads();
    unsigned short* dst = dst0 + (size_t)(nt * 32) * K + kt * 32;
#pragma unroll
    for (int i = 0; i < 4; i++) dst[(size_t)(r + i * 8) * K + c] = f2b(tile[c][r + i * 8]);
}

// ---------- xd = causal diff of x, emitted bf16 ----------
__global__ __launch_bounds__(256) void diff_k(const float* __restrict__ x,
                                              unsigned short* __restrict__ xd) {
    size_t idx = (size_t)blockIdx.x * 256 + threadIdx.x;   // over 8192*512
    int l = (int)((idx >> 9) & 255);
    float v = x[idx];
    if (l > 0) v -= x[idx - 512];
    xd[idx] = f2b(v);
}

// ---------- adjacency: softmax(relu(e1 @ e2^T)) ----------
__global__ __launch_bounds__(256) void adj_k(const float* __restrict__ e1,
                                             const float* __restrict__ e2,
                                             float* __restrict__ adjf,
                                             unsigned short* __restrict__ adjb) {
    const int n = blockIdx.x, tid = threadIdx.x;
    __shared__ float e1s[16];
    __shared__ float redm[4], reds[4];
    if (tid < 16) e1s[tid] = e1[n * 16 + tid];
    __syncthreads();
    const float* e2r = e2 + tid * 16;
    float dot = 0.f;
#pragma unroll
    for (int k = 0; k < 16; k++) dot = fmaf(e1s[k], e2r[k], dot);
    float v = fmaxf(dot, 0.f);
    float m = v;
#pragma unroll
    for (int o = 32; o > 0; o >>= 1) m = fmaxf(m, __shfl_xor(m, o));
    const int lane = tid & 63, wv = tid >> 6;
    if (lane == 0) redm[wv] = m;
    __syncthreads();
    m = fmaxf(fmaxf(redm[0], redm[1]), fmaxf(redm[2], redm[3]));
    float e = __expf(v - m);
    float ssum = e;
#pragma unroll
    for (int o = 32; o > 0; o >>= 1) ssum += __shfl_xor(ssum, o);
    if (lane == 0) reds[wv] = ssum;
    __syncthreads();
    ssum = reds[0] + reds[1] + reds[2] + reds[3];
    float o = e / ssum;
    adjf[(size_t)n * 256 + tid] = o;
    adjb[(size_t)n * 256 + tid] = f2b(o);
}

// ---------- bf16 MFMA GEMM: C = A(M,K) @ B(K,N), B given transposed (N,K) ----------
// 4 waves; wave (wr,wc) computes FMx16 x FNx16; BK=32 -> one 16x16x32 mfma per frag/step
template<int BM, int BN, int BK, int WRN, int FM, int FN,
         int OBF, int HBIAS, int HGELU, int HRES>
__global__ __launch_bounds__(256) void gemm_k(
    const unsigned short* __restrict__ A, const unsigned short* __restrict__ Bt,
    void* __restrict__ C, const float* __restrict__ bias, const float* __restrict__ res,
    int M, int N, int K, long sA, long sB, long sC) {
    __shared__ __align__(16) unsigned short As[BM * BK];
    __shared__ __align__(16) unsigned short Bs[BN * BK];
    const int tid  = threadIdx.x;
    const int lane = tid & 63;
    const int wave = tid >> 6;
    const int wr = wave / WRN, wc = wave % WRN;
    const int bm = blockIdx.x * BM, bn = blockIdx.y * BN;
    const unsigned short* Ab = A  + (size_t)blockIdx.z * sA;
    const unsigned short* Bb = Bt + (size_t)blockIdx.z * sB;
    const int lrow = lane & 15;
    const int kof  = (lane >> 4) << 3;

    f32x4 acc[FM][FN];
#pragma unroll
    for (int m = 0; m < FM; m++)
#pragma unroll
        for (int n = 0; n < FN; n++) {
            acc[m][n][0] = 0.f; acc[m][n][1] = 0.f; acc[m][n][2] = 0.f; acc[m][n][3] = 0.f;
        }

    constexpr int AI = (BM * BK) / 2048;   // 8 bf16 per thread per iter, 256 threads
    constexpr int BI = (BN * BK) / 2048;

    for (int k0 = 0; k0 < K; k0 += BK) {
#pragma unroll
        for (int it = 0; it < AI; ++it) {
            int flat = (it * 256 + tid) * 8;
            int r = flat / BK, c = flat % BK;
            gload_lds16(Ab + (size_t)(bm + r) * K + (k0 + c),
                        &As[(it * 256 + (tid & 192)) * 8]);
        }
#pragma unroll
        for (int it = 0; it < BI; ++it) {
            int flat = (it * 256 + tid) * 8;
            int r = flat / BK, c = flat % BK;
            gload_lds16(Bb + (size_t)(bn + r) * K + (k0 + c),
                        &Bs[(it * 256 + (tid & 192)) * 8]);
        }
        __syncthreads();
        bf16x8 af[FM], bfv[FN];
#pragma unroll
        for (int m = 0; m < FM; m++)
            af[m] = *(const bf16x8*)&As[(wr * FM * 16 + m * 16 + lrow) * BK + kof];
#pragma unroll
        for (int n = 0; n < FN; n++)
            bfv[n] = *(const bf16x8*)&Bs[(wc * FN * 16 + n * 16 + lrow) * BK + kof];
#pragma unroll
        for (int m = 0; m < FM; m++)
#pragma unroll
            for (int n = 0; n < FN; n++)
                acc[m][n] = __builtin_amdgcn_mfma_f32_16x16x32_bf16(af[m], bfv[n], acc[m][n], 0, 0, 0);
        __syncthreads();
    }

    const int r0 = (lane >> 4) << 2;
#pragma unroll
    for (int n = 0; n < FN; n++) {
        const int ccol = bn + wc * FN * 16 + n * 16 + lrow;
        float bv = 0.f;
        if (HBIAS) bv = bias[ccol];
#pragma unroll
        for (int m = 0; m < FM; m++) {
#pragma unroll
            for (int j = 0; j < 4; j++) {
                const int rrow = bm + wr * FM * 16 + m * 16 + r0 + j;
                float v = acc[m][n][j] + bv;
                if (HGELU) v = geluf_(v);
                if (HRES)  v += res[(size_t)rrow * N + ccol];
                size_t oi = (size_t)blockIdx.z * sC + (size_t)rrow * N + ccol;
                if (OBF) ((unsigned short*)C)[oi] = f2b(v);
                else     ((float*)C)[oi] = v;
            }
        }
    }
}

// ---------- depthwise causal conv1d (width 4) + bias + silu, bf16 in/out ----------
__global__ __launch_bounds__(256) void conv_k(const unsigned short* __restrict__ uz,
                                              const float* __restrict__ w,
                                              const float* __restrict__ cb,
                                              unsigned short* __restrict__ u) {
    size_t idx = (size_t)blockIdx.x * 256 + threadIdx.x;   // over 8192*1024
    int d = (int)(idx & 1023);
    size_t row = idx >> 10;
    int l = (int)(row & 255);
    float acc = cb[d];
#pragma unroll
    for (int k = 0; k < 4; k++) {
        int ls = l + k - 3;
        if (ls >= 0) {
            long rr = (long)row + k - 3;
            acc = fmaf(w[d * 4 + k], b2f(uz[((size_t)rr << 11) + d]), acc);
        }
    }
    u[idx] = f2b(acc * sigmoidf_(acc));
}

// ---------- fused dt-proj + softplus + selective scan + D-skip + z-gate ----------
// one wave per (b, 64 channels); proj row (64 f32) staged in LDS per step
__global__ __launch_bounds__(64) void scan_k(
    const float* __restrict__ proj,     // (8192, 64): [dt(32) | B(16) | C(16)]
    const float* __restrict__ dt_w,     // (32, 1024)
    const float* __restrict__ dt_b,     // (1024)
    const float* __restrict__ A_log,    // (1024, 16)
    const float* __restrict__ Dp,       // (1024)
    const unsigned short* __restrict__ uz,  // (8192, 2048) -> z at col 1024+d
    const unsigned short* __restrict__ u,   // (8192, 1024)
    unsigned short* __restrict__ yg) {      // (8192, 1024)
    const int d = blockIdx.x * 64 + threadIdx.x;
    const int b = blockIdx.y;
    float w[32];
#pragma unroll
    for (int r = 0; r < 32; r++) w[r] = dt_w[r * 1024 + d];
    const float dtb = dt_b[d], Dd = Dp[d];
    float Aa[16];
#pragma unroll
    for (int s = 0; s < 16; s++) Aa[s] = -__expf(A_log[d * 16 + s]);
    float h[16];
#pragma unroll
    for (int s = 0; s < 16; s++) h[s] = 0.f;
    __shared__ float pl[64];
    const size_t base = (size_t)b * 256;
    for (int l = 0; l < 256; l++) {
        const size_t row = base + l;
        __syncthreads();
        if (threadIdx.x < 16)
            ((float4*)pl)[threadIdx.x] = ((const float4*)(proj + row * 64))[threadIdx.x];
        __syncthreads();
        float dtr = dtb;
#pragma unroll
        for (int r = 0; r < 32; r++) dtr = fmaf(w[r], pl[r], dtr);
        const float dt = dtr > 15.f ? dtr : log1pf(__expf(dtr));   // softplus
        const float uu = b2f(u[(row << 10) + d]);
        const float zz = b2f(uz[(row << 11) + 1024 + d]);
        const float du = dt * uu;
        float y = 0.f;
#pragma unroll
        for (int s = 0; s < 16; s++) {
            h[s] = __expf(dt * Aa[s]) * h[s] + du * pl[32 + s];
            y = fmaf(h[s], pl[48 + s], y);
        }
        y = fmaf(uu, Dd, y);
        yg[(row << 10) + d] = f2b(y * (zz * sigmoidf_(zz)));
    }
}

// ---------- residual-add + layernorm ----------
template<int HRES, int OF32, int OBF>
__global__ __launch_bounds__(256) void ln_k(const float* __restrict__ xin,
                                            const float* __restrict__ resin,
                                            const float* __restrict__ g,
                                            const float* __restrict__ b,
                                            float* __restrict__ outf,
                                            unsigned short* __restrict__ outb) {
    const int row = blockIdx.x, tid = threadIdx.x;
    float2 v = ((const float2*)(xin + (size_t)row * 512))[tid];
    if (HRES) {
        float2 r2 = ((const float2*)(resin + (size_t)row * 512))[tid];
        v.x += r2.x; v.y += r2.y;
    }
    float s = v.x + v.y, q = v.x * v.x + v.y * v.y;
#pragma unroll
    for (int o = 32; o > 0; o >>= 1) { s += __shfl_xor(s, o); q += __shfl_xor(q, o); }
    __shared__ float sm[4], qm[4];
    const int lane = tid & 63, wv = tid >> 6;
    if (lane == 0) { sm[wv] = s; qm[wv] = q; }
    __syncthreads();
    s = sm[0] + sm[1] + sm[2] + sm[3];
    q = qm[0] + qm[1] + qm[2] + qm[3];
    const float mu = s * (1.f / 512.f);
    const float ri = rsqrtf(q * (1.f / 512.f) - mu * mu + 1e-5f);
    float2 gg = ((const float2*)g)[tid];
    float2 bb = ((const float2*)b)[tid];
    float o0 = (v.x - mu) * ri * gg.x + bb.x;
    float o1 = (v.y - mu) * ri * gg.y + bb.y;
    if (OF32) ((float2*)(outf + (size_t)row * 512))[tid] = make_float2(o0, o1);
    if (OBF) {
        unsigned short* ob = outb + (size_t)row * 512 + tid * 2;
        ob[0] = f2b(o0); ob[1] = f2b(o1);
    }
}

// ---------- per-batch transpose x1 (b,l,d) f32 -> (b,d,l) bf16 ----------
__global__ __launch_bounds__(256) void trans_k(const float* __restrict__ x1,
                                               unsigned short* __restrict__ xt) {
    __shared__ float tile[32][33];
    const int b = blockIdx.z;
    const int d0 = blockIdx.x * 32, l0 = blockIdx.y * 32;
    const int c = threadIdx.x & 31, r = threadIdx.x >> 5;
    const float* src = x1 + ((size_t)b * 256 + l0) * 512 + d0;
#pragma unroll
    for (int i = 0; i < 4; i++) tile[r + i * 8][c] = src[(size_t)(r + i * 8) * 512 + c];
    __syncthreads();
    unsigned short* dst = xt + ((size_t)b * 512 + d0) * 256 + l0;
#pragma unroll
    for (int i = 0; i < 4; i++) dst[(size_t)(r + i * 8) * 256 + c] = f2b(tile[c][r + i * 8]);
}

// ---------- workspace layout (bytes) ----------
constexpr size_t OFF_WT_DIN  = 0;
constexpr size_t OFF_WT_SIN  = OFF_WT_DIN  + 2048ull * 512 * 2;
constexpr size_t OFF_WT_DXP  = OFF_WT_SIN  + 2048ull * 512 * 2;
constexpr size_t OFF_WT_SXP  = OFF_WT_DXP  + 64ull * 1024 * 2;
constexpr size_t OFF_WT_DOUT = OFF_WT_SXP  + 64ull * 1024 * 2;
constexpr size_t OFF_WT_SOUT = OFF_WT_DOUT + 512ull * 1024 * 2;
constexpr size_t OFF_WT_F1   = OFF_WT_SOUT + 512ull * 1024 * 2;
constexpr size_t OFF_WT_F2   = OFF_WT_F1   + 2048ull * 512 * 2;
constexpr size_t OFF_ACT     = OFF_WT_F2   + 512ull * 2048 * 2;   // xd / xg bf16 (8192x512)
constexpr size_t OFF_UZ      = OFF_ACT  + 8192ull * 512 * 2;      // uz bf16 (8192x2048); reused as FFN mid
constexpr size_t OFF_U       = OFF_UZ   + 8192ull * 2048 * 2;     // u bf16 (8192x1024); reused as h bf16
constexpr size_t OFF_PROJ    = OFF_U    + 8192ull * 1024 * 2;     // proj f32 (8192x64)
constexpr size_t OFF_YG      = OFF_PROJ + 8192ull * 64 * 4;       // gated y bf16 (8192x1024)
constexpr size_t OFF_MOUT    = OFF_YG   + 8192ull * 1024 * 2;     // mamba out f32 (8192x512)
constexpr size_t OFF_X1      = OFF_MOUT + 8192ull * 512 * 4;      // x1 f32
constexpr size_t OFF_X2      = OFF_X1   + 8192ull * 512 * 4;      // x2 f32
constexpr size_t OFF_X1T     = OFF_X2   + 8192ull * 512 * 4;      // x1^T bf16 (32,512,256)
constexpr size_t OFF_ADJB    = OFF_X1T  + 32ull * 512 * 256 * 2;  // adj bf16 (256x256)

extern "C" void kernel_launch(void* const* d_in, const int* in_sizes, int n_in,
                              void* d_out, int out_size, void* d_ws, size_t ws_size,
                              hipStream_t stream) {
    (void)in_sizes; (void)n_in; (void)out_size; (void)ws_size;
    const float* x      = (const float*)d_in[0];
    const float* dinw   = (const float*)d_in[1];
    const float* dconvw = (const float*)d_in[2];
    const float* dconvb = (const float*)d_in[3];
    const float* dxproj = (const float*)d_in[4];
    const float* ddtw   = (const float*)d_in[5];
    const float* ddtb   = (const float*)d_in[6];
    const float* dAlog  = (const float*)d_in[7];
    const float* dD     = (const float*)d_in[8];
    const float* doutw  = (const float*)d_in[9];
    const float* dlng   = (const float*)d_in[10];
    const float* dlnb   = (const float*)d_in[11];
    const float* sinw   = (const float*)d_in[12];
    const float* sconvw = (const float*)d_in[13];
    const float* sconvb = (const float*)d_in[14];
    const float* sxproj = (const float*)d_in[15];
    const float* sdtw   = (const float*)d_in[16];
    const float* sdtb   = (const float*)d_in[17];
    const float* sAlog  = (const float*)d_in[18];
    const float* sD     = (const float*)d_in[19];
    const float* soutw  = (const float*)d_in[20];
    const float* slng   = (const float*)d_in[21];
    const float* slnb   = (const float*)d_in[22];
    const float* semb1  = (const float*)d_in[23];
    const float* semb2  = (const float*)d_in[24];
    const float* flng   = (const float*)d_in[25];
    const float* flnb   = (const float*)d_in[26];
    const float* fw1    = (const float*)d_in[27];
    const float* fb1    = (const float*)d_in[28];
    const float* fw2    = (const float*)d_in[29];
    const float* fb2    = (const float*)d_in[30];

    char* ws = (char*)d_ws;
    unsigned short* wtDin  = (unsigned short*)(ws + OFF_WT_DIN);
    unsigned short* wtSin  = (unsigned short*)(ws + OFF_WT_SIN);
    unsigned short* wtDxp  = (unsigned short*)(ws + OFF_WT_DXP);
    unsigned short* wtSxp  = (unsigned short*)(ws + OFF_WT_SXP);
    unsigned short* wtDout = (unsigned short*)(ws + OFF_WT_DOUT);
    unsigned short* wtSout = (unsigned short*)(ws + OFF_WT_SOUT);
    unsigned short* wtF1   = (unsigned short*)(ws + OFF_WT_F1);
    unsigned short* wtF2   = (unsigned short*)(ws + OFF_WT_F2);
    unsigned short* actIn  = (unsigned short*)(ws + OFF_ACT);
    unsigned short* uzBuf  = (unsigned short*)(ws + OFF_UZ);
    unsigned short* uBuf   = (unsigned short*)(ws + OFF_U);
    float*          projB  = (float*)(ws + OFF_PROJ);
    unsigned short* ygBuf  = (unsigned short*)(ws + OFF_YG);
    float*          moutB  = (float*)(ws + OFF_MOUT);
    float*          x1Buf  = (float*)(ws + OFF_X1);
    float*          x2Buf  = (float*)(ws + OFF_X2);
    unsigned short* x1tBuf = (unsigned short*)(ws + OFF_X1T);
    unsigned short* adjB   = (unsigned short*)(ws + OFF_ADJB);
    unsigned short* hBuf   = uBuf;    // reuse (u dead after scan2)
    unsigned short* midBuf = uzBuf;   // reuse (uz dead after scan2)

    float* outX   = (float*)d_out;
    float* outAdj = outX + 4194304;

    // 1) weight transposes/converts (one launch)
    WtArgs wa;
    wa.m[0] = WtDesc{dinw,   wtDin,  512, 2048, 0};
    wa.m[1] = WtDesc{sinw,   wtSin,  512, 2048, 1024};
    wa.m[2] = WtDesc{dxproj, wtDxp, 1024, 64,   2048};
    wa.m[3] = WtDesc{sxproj, wtSxp, 1024, 64,   2112};
    wa.m[4] = WtDesc{doutw,  wtDout,1024, 512,  2176};
    wa.m[5] = WtDesc{soutw,  wtSout,1024, 512,  2688};
    wa.m[6] = WtDesc{fw1,    wtF1,   512, 2048, 3200};
    wa.m[7] = WtDesc{fw2,    wtF2,  2048, 512,  4224};
    wtrans_k<<<dim3(5248), dim3(256), 0, stream>>>(wa);

    // 2) xd, 3) adjacency
    diff_k<<<dim3(16384), dim3(256), 0, stream>>>(x, actIn);
    adj_k<<<dim3(256), dim3(256), 0, stream>>>(semb1, semb2, outAdj, adjB);

    // ---- stage 1: DiffSSM mamba ----
    gemm_k<128,128,32,2,4,4, 1,0,0,0><<<dim3(64,16,1), dim3(256), 0, stream>>>(
        actIn, wtDin, uzBuf, nullptr, nullptr, 8192, 2048, 512, 0, 0, 0);
    conv_k<<<dim3(32768), dim3(256), 0, stream>>>(uzBuf, dconvw, dconvb, uBuf);
    gemm_k<64,64,32,2,2,2, 0,0,0,0><<<dim3(128,1,1), dim3(256), 0, stream>>>(
        uBuf, wtDxp, projB, nullptr, nullptr, 8192, 64, 1024, 0, 0, 0);
    scan_k<<<dim3(16,32), dim3(64), 0, stream>>>(projB, ddtw, ddtb, dAlog, dD, uzBuf, uBuf, ygBuf);
    gemm_k<128,128,32,2,4,4, 0,0,0,0><<<dim3(64,4,1), dim3(256), 0, stream>>>(
        ygBuf, wtDout, moutB, nullptr, nullptr, 8192, 512, 1024, 0, 0, 0);
    ln_k<1,1,0><<<dim3(8192), dim3(256), 0, stream>>>(moutB, x, dlng, dlnb, x1Buf, nullptr);

    // ---- stage 2: SpatialGraphMamba ----
    trans_k<<<dim3(16,8,32), dim3(256), 0, stream>>>(x1Buf, x1tBuf);
    gemm_k<128,128,32,2,4,4, 1,0,0,0><<<dim3(2,4,32), dim3(256), 0, stream>>>(
        adjB, x1tBuf, actIn, nullptr, nullptr, 256, 512, 256, 0, 131072, 131072);
    gemm_k<128,128,32,2,4,4, 1,0,0,0><<<dim3(64,16,1), dim3(256), 0, stream>>>(
        actIn, wtSin, uzBuf, nullptr, nullptr, 8192, 2048, 512, 0, 0, 0);
    conv_k<<<dim3(32768), dim3(256), 0, stream>>>(uzBuf, sconvw, sconvb, uBuf);
    gemm_k<64,64,32,2,2,2, 0,0,0,0><<<dim3(128,1,1), dim3(256), 0, stream>>>(
        uBuf, wtSxp, projB, nullptr, nullptr, 8192, 64, 1024, 0, 0, 0);
    scan_k<<<dim3(16,32), dim3(64), 0, stream>>>(projB, sdtw, sdtb, sAlog, sD, uzBuf, uBuf, ygBuf);
    gemm_k<128,128,32,2,4,4, 0,0,0,0><<<dim3(64,4,1), dim3(256), 0, stream>>>(
        ygBuf, wtSout, moutB, nullptr, nullptr, 8192, 512, 1024, 0, 0, 0);
    ln_k<1,1,0><<<dim3(8192), dim3(256), 0, stream>>>(moutB, x1Buf, slng, slnb, x2Buf, nullptr);

    // ---- stage 3: FFN ----
    ln_k<0,0,1><<<dim3(8192), dim3(256), 0, stream>>>(x2Buf, nullptr, flng, flnb, nullptr, hBuf);
    gemm_k<128,128,32,2,4,4, 1,1,1,0><<<dim3(64,16,1), dim3(256), 0, stream>>>(
        hBuf, wtF1, midBuf, fb1, nullptr, 8192, 2048, 512, 0, 0, 0);
    gemm_k<128,128,32,2,4,4, 0,1,0,1><<<dim3(64,4,1), dim3(256), 0, stream>>>(
        midBuf, wtF2, outX, fb2, x2Buf, 8192, 512, 2048, 0, 0, 0);
}

// Round 2
// 715.365 us; speedup vs baseline: 1.5597x; 1.5597x over previous
//
#include <hip/hip_runtime.h>

#define DEV __device__ __forceinline__

typedef __bf16 bf16x8 __attribute__((ext_vector_type(8)));
typedef float  f32x4  __attribute__((ext_vector_type(4)));

// ---------- helpers ----------
DEV unsigned short f2b(float f) {                 // f32 -> bf16 (RNE)
    union { float f; unsigned u; } v; v.f = f;
    unsigned r = v.u + 0x7fffu + ((v.u >> 16) & 1u);
    return (unsigned short)(r >> 16);
}
DEV float b2f(unsigned short h) {
    union { unsigned u; float f; } v; v.u = ((unsigned)h) << 16;
    return v.f;
}
DEV float sigmoidf_(float x) { return 1.f / (1.f + __expf(-x)); }
DEV float geluf_(float x) {                       // jax default: tanh approximation
    float t = 0.7978845608028654f * (x + 0.044715f * x * x * x);
    return 0.5f * x * (1.f + tanhf(t));
}
DEV float softplusf_(float x) { return x > 15.f ? x : log1pf(__expf(x)); }
DEV void gload_lds16(const void* g, void* l) {
    __builtin_amdgcn_global_load_lds((const __attribute__((address_space(1))) void*)g,
                                     (__attribute__((address_space(3))) void*)l, 16, 0, 0);
}

// ---------- problem constants ----------
// B=32 L=256 D=512 D_INNER=1024 D_STATE=16 DT_RANK=32 D_FF=2048, M = B*L = 8192
// scan chunking: NC=8 chunks of LC=32

// ---------- weight transpose+convert: W (K,N) f32 -> W^T (N,K) bf16 ----------
struct WtDesc { const float* s; unsigned short* d; int K; int N; int t0; };
struct WtArgs { WtDesc m[8]; };

__global__ __launch_bounds__(256) void wtrans_k(WtArgs a) {
    __shared__ float tile[32][33];
    int t = blockIdx.x;
    int mi = 0;
#pragma unroll
    for (int j = 1; j < 8; j++) if (t >= a.m[j].t0) mi = j;
    const float* src0 = a.m[mi].s;
    unsigned short* dst0 = a.m[mi].d;
    const int K = a.m[mi].K, N = a.m[mi].N;
    const int lt = t - a.m[mi].t0;
    const int ntk = K >> 5;
    const int kt = lt % ntk, nt = lt / ntk;
    const int c = threadIdx.x & 31, r = threadIdx.x >> 5;
    const float* src = src0 + (size_t)(kt * 32) * N + nt * 32;
#pragma unroll
    for (int i = 0; i < 4; i++) tile[r + i * 8][c] = src[(size_t)(r + i * 8) * N + c];
    __syncthreads();
    unsigned short* dst = dst0 + (size_t)(nt * 32) * K + kt * 32;
#pragma unroll
    for (int i = 0; i < 4; i++) dst[(size_t)(r + i * 8) * K + c] = f2b(tile[c][r + i * 8]);
}

// ---------- compose: Weff^T[d][k] = sum_r xproj[k][r]*dtw[r][d]; Wbc^T[n][k] ----------
__global__ __launch_bounds__(256) void compose_k(const float* __restrict__ xproj,  // (1024,64)
                                                 const float* __restrict__ dtw,    // (32,1024)
                                                 unsigned short* __restrict__ weff, // (1024,1024)
                                                 unsigned short* __restrict__ wbc) { // (64,1024)
    const int r0 = blockIdx.x;
    if (r0 < 1024) {
        const int d = r0;
        for (int kb = 0; kb < 4; kb++) {
            int k = kb * 256 + threadIdx.x;
            float acc = 0.f;
#pragma unroll
            for (int r = 0; r < 32; r++)
                acc = fmaf(xproj[k * 64 + r], dtw[r * 1024 + d], acc);
            weff[(size_t)d * 1024 + k] = f2b(acc);
        }
    } else {
        const int n = r0 - 1024;
        for (int kb = 0; kb < 4; kb++) {
            int k = kb * 256 + threadIdx.x;
            wbc[(size_t)n * 1024 + k] = (n < 32) ? f2b(xproj[k * 64 + 32 + n]) : (unsigned short)0;
        }
    }
}

// ---------- xd = causal diff of x, emitted bf16 ----------
__global__ __launch_bounds__(256) void diff_k(const float* __restrict__ x,
                                              unsigned short* __restrict__ xd) {
    size_t idx = (size_t)blockIdx.x * 256 + threadIdx.x;   // over 8192*512
    int l = (int)((idx >> 9) & 255);
    float v = x[idx];
    if (l > 0) v -= x[idx - 512];
    xd[idx] = f2b(v);
}

// ---------- adjacency: softmax(relu(e1 @ e2^T)) ----------
__global__ __launch_bounds__(256) void adj_k(const float* __restrict__ e1,
                                             const float* __restrict__ e2,
                                             float* __restrict__ adjf,
                                             unsigned short* __restrict__ adjb) {
    const int n = blockIdx.x, tid = threadIdx.x;
    __shared__ float e1s[16];
    __shared__ float redm[4], reds[4];
    if (tid < 16) e1s[tid] = e1[n * 16 + tid];
    __syncthreads();
    const float* e2r = e2 + tid * 16;
    float dot = 0.f;
#pragma unroll
    for (int k = 0; k < 16; k++) dot = fmaf(e1s[k], e2r[k], dot);
    float v = fmaxf(dot, 0.f);
    float m = v;
#pragma unroll
    for (int o = 32; o > 0; o >>= 1) m = fmaxf(m, __shfl_xor(m, o));
    const int lane = tid & 63, wv = tid >> 6;
    if (lane == 0) redm[wv] = m;
    __syncthreads();
    m = fmaxf(fmaxf(redm[0], redm[1]), fmaxf(redm[2], redm[3]));
    float e = __expf(v - m);
    float ssum = e;
#pragma unroll
    for (int o = 32; o > 0; o >>= 1) ssum += __shfl_xor(ssum, o);
    if (lane == 0) reds[wv] = ssum;
    __syncthreads();
    ssum = reds[0] + reds[1] + reds[2] + reds[3];
    float o = e / ssum;
    adjf[(size_t)n * 256 + tid] = o;
    adjb[(size_t)n * 256 + tid] = f2b(o);
}

// ---------- bf16 MFMA GEMM: C = A(M,K) @ B(K,N), B given transposed (N,K) ----------
template<int BM, int BN, int BK, int WRN, int FM, int FN,
         int OBF, int HBIAS, int HGELU, int HRES, int HSP>
__global__ __launch_bounds__(256) void gemm_k(
    const unsigned short* __restrict__ A, const unsigned short* __restrict__ Bt,
    void* __restrict__ C, const float* __restrict__ bias, const float* __restrict__ res,
    int M, int N, int K, long sA, long sB, long sC) {
    __shared__ __align__(16) unsigned short As[BM * BK];
    __shared__ __align__(16) unsigned short Bs[BN * BK];
    const int tid  = threadIdx.x;
    const int lane = tid & 63;
    const int wave = tid >> 6;
    const int wr = wave / WRN, wc = wave % WRN;
    const int bm = blockIdx.x * BM, bn = blockIdx.y * BN;
    const unsigned short* Ab = A  + (size_t)blockIdx.z * sA;
    const unsigned short* Bb = Bt + (size_t)blockIdx.z * sB;
    const int lrow = lane & 15;
    const int kof  = (lane >> 4) << 3;

    f32x4 acc[FM][FN];
#pragma unroll
    for (int m = 0; m < FM; m++)
#pragma unroll
        for (int n = 0; n < FN; n++) {
            acc[m][n][0] = 0.f; acc[m][n][1] = 0.f; acc[m][n][2] = 0.f; acc[m][n][3] = 0.f;
        }

    constexpr int AI = (BM * BK) / 2048;
    constexpr int BI = (BN * BK) / 2048;

    for (int k0 = 0; k0 < K; k0 += BK) {
#pragma unroll
        for (int it = 0; it < AI; ++it) {
            int flat = (it * 256 + tid) * 8;
            int r = flat / BK, c = flat % BK;
            gload_lds16(Ab + (size_t)(bm + r) * K + (k0 + c),
                        &As[(it * 256 + (tid & 192)) * 8]);
        }
#pragma unroll
        for (int it = 0; it < BI; ++it) {
            int flat = (it * 256 + tid) * 8;
            int r = flat / BK, c = flat % BK;
            gload_lds16(Bb + (size_t)(bn + r) * K + (k0 + c),
                        &Bs[(it * 256 + (tid & 192)) * 8]);
        }
        __syncthreads();
        bf16x8 af[FM], bfv[FN];
#pragma unroll
        for (int m = 0; m < FM; m++)
            af[m] = *(const bf16x8*)&As[(wr * FM * 16 + m * 16 + lrow) * BK + kof];
#pragma unroll
        for (int n = 0; n < FN; n++)
            bfv[n] = *(const bf16x8*)&Bs[(wc * FN * 16 + n * 16 + lrow) * BK + kof];
#pragma unroll
        for (int m = 0; m < FM; m++)
#pragma unroll
            for (int n = 0; n < FN; n++)
                acc[m][n] = __builtin_amdgcn_mfma_f32_16x16x32_bf16(af[m], bfv[n], acc[m][n], 0, 0, 0);
        __syncthreads();
    }

    const int r0 = (lane >> 4) << 2;
#pragma unroll
    for (int n = 0; n < FN; n++) {
        const int ccol = bn + wc * FN * 16 + n * 16 + lrow;
        float bv = 0.f;
        if (HBIAS) bv = bias[ccol];
#pragma unroll
        for (int m = 0; m < FM; m++) {
#pragma unroll
            for (int j = 0; j < 4; j++) {
                const int rrow = bm + wr * FM * 16 + m * 16 + r0 + j;
                float v = acc[m][n][j] + bv;
                if (HSP)   v = softplusf_(v);
                if (HGELU) v = geluf_(v);
                if (HRES)  v += res[(size_t)rrow * N + ccol];
                size_t oi = (size_t)blockIdx.z * sC + (size_t)rrow * N + ccol;
                if (OBF) ((unsigned short*)C)[oi] = f2b(v);
                else     ((float*)C)[oi] = v;
            }
        }
    }
}

// ---------- depthwise causal conv1d (width 4) + bias + silu, bf16 in/out ----------
__global__ __launch_bounds__(256) void conv_k(const unsigned short* __restrict__ uz,
                                              const float* __restrict__ w,
                                              const float* __restrict__ cb,
                                              unsigned short* __restrict__ u) {
    size_t idx = (size_t)blockIdx.x * 256 + threadIdx.x;   // over 8192*1024
    int d = (int)(idx & 1023);
    size_t row = idx >> 10;
    int l = (int)(row & 255);
    float acc = cb[d];
#pragma unroll
    for (int k = 0; k < 4; k++) {
        int ls = l + k - 3;
        if (ls >= 0) {
            long rr = (long)row + k - 3;
            acc = fmaf(w[d * 4 + k], b2f(uz[((size_t)rr << 11) + d]), acc);
        }
    }
    u[idx] = f2b(acc * sigmoidf_(acc));
}

// ---------- chunked selective scan ----------
// pass 1: per-chunk local scan (h0=0) -> hend (b,c,d,16), Sc (b,c,d) = sum dt
__global__ __launch_bounds__(256) void scan1_k(
    const float* __restrict__ dt,          // (8192,1024) f32
    const unsigned short* __restrict__ u,  // (8192,1024) bf16
    const float* __restrict__ proj,        // (8192,64) f32: B at 0..15
    const float* __restrict__ A_log,       // (1024,16)
    float* __restrict__ hend,              // (32,8,1024,16)
    float* __restrict__ Sc) {              // (32,8,1024)
    const int dg = blockIdx.x, c = blockIdx.y, b = blockIdx.z;
    const int d = dg * 256 + threadIdx.x;
    const size_t base = (size_t)b * 256 + c * 32;
    __shared__ float Bs[32][16];
    for (int i = threadIdx.x; i < 512; i += 256) {
        int r = i >> 4, s = i & 15;
        Bs[r][s] = proj[(base + r) * 64 + s];
    }
    __syncthreads();
    float Aa[16];
#pragma unroll
    for (int s = 0; s < 16; s++) Aa[s] = -__expf(A_log[d * 16 + s]);
    float h[16];
#pragma unroll
    for (int s = 0; s < 16; s++) h[s] = 0.f;
    float ssum = 0.f;
    for (int l = 0; l < 32; l++) {
        size_t row = base + l;
        float dtv = dt[(row << 10) + d];
        float uu  = b2f(u[(row << 10) + d]);
        float du  = dtv * uu;
        ssum += dtv;
#pragma unroll
        for (int s = 0; s < 16; s++)
            h[s] = __expf(dtv * Aa[s]) * h[s] + du * Bs[l][s];
    }
    size_t o = (size_t)(b * 8 + c) * 1024 + d;
    Sc[o] = ssum;
#pragma unroll
    for (int s = 0; s < 16; s++) hend[o * 16 + s] = h[s];
}

// pass 2: propagate chunk-start states sequentially over the 8 chunks
__global__ __launch_bounds__(256) void scan2_k(
    const float* __restrict__ hend, const float* __restrict__ Sc,
    const float* __restrict__ A_log, float* __restrict__ hstart) {
    const int d = blockIdx.x * 256 + threadIdx.x;
    const int b = blockIdx.y;
    float Aa[16];
#pragma unroll
    for (int s = 0; s < 16; s++) Aa[s] = -__expf(A_log[d * 16 + s]);
    float h[16];
#pragma unroll
    for (int s = 0; s < 16; s++) h[s] = 0.f;
    for (int c = 0; c < 8; c++) {
        size_t o = (size_t)(b * 8 + c) * 1024 + d;
#pragma unroll
        for (int s = 0; s < 16; s++) hstart[o * 16 + s] = h[s];
        float sc = Sc[o];
#pragma unroll
        for (int s = 0; s < 16; s++)
            h[s] = __expf(sc * Aa[s]) * h[s] + hend[o * 16 + s];
    }
}

// pass 3: recompute local scans with correct h_start; fused y=h.C + u*D, z-gate
__global__ __launch_bounds__(256) void scan3_k(
    const float* __restrict__ dt,
    const unsigned short* __restrict__ u,
    const unsigned short* __restrict__ uz,   // z at col 1024+d
    const float* __restrict__ proj,          // B at 0..15, C at 16..31
    const float* __restrict__ A_log,
    const float* __restrict__ Dp,
    const float* __restrict__ hstart,
    unsigned short* __restrict__ yg) {
    const int dg = blockIdx.x, c = blockIdx.y, b = blockIdx.z;
    const int d = dg * 256 + threadIdx.x;
    const size_t base = (size_t)b * 256 + c * 32;
    __shared__ float BCs[32][32];
    for (int i = threadIdx.x; i < 1024; i += 256) {
        int r = i >> 5, s = i & 31;
        BCs[r][s] = proj[(base + r) * 64 + s];
    }
    __syncthreads();
    float Aa[16];
#pragma unroll
    for (int s = 0; s < 16; s++) Aa[s] = -__expf(A_log[d * 16 + s]);
    const float Dd = Dp[d];
    float h[16];
    size_t ho = ((size_t)(b * 8 + c) * 1024 + d) * 16;
#pragma unroll
    for (int s = 0; s < 16; s++) h[s] = hstart[ho + s];
    for (int l = 0; l < 32; l++) {
        size_t row = base + l;
        float dtv = dt[(row << 10) + d];
        float uu  = b2f(u[(row << 10) + d]);
        float zz  = b2f(uz[(row << 11) + 1024 + d]);
        float du  = dtv * uu;
        float y = 0.f;
#pragma unroll
        for (int s = 0; s < 16; s++) {
            h[s] = __expf(dtv * Aa[s]) * h[s] + du * BCs[l][s];
            y = fmaf(h[s], BCs[l][16 + s], y);
        }
        y = fmaf(uu, Dd, y);
        yg[(row << 10) + d] = f2b(y * (zz * sigmoidf_(zz)));
    }
}

// ---------- residual-add + layernorm ----------
template<int HRES, int OF32, int OBF>
__global__ __launch_bounds__(256) void ln_k(const float* __restrict__ xin,
                                            const float* __restrict__ resin,
                                            const float* __restrict__ g,
                                            const float* __restrict__ b,
                                            float* __restrict__ outf,
                                            unsigned short* __restrict__ outb) {
    const int row = blockIdx.x, tid = threadIdx.x;
    float2 v = ((const float2*)(xin + (size_t)row * 512))[tid];
    if (HRES) {
        float2 r2 = ((const float2*)(resin + (size_t)row * 512))[tid];
        v.x += r2.x; v.y += r2.y;
    }
    float s = v.x + v.y, q = v.x * v.x + v.y * v.y;
#pragma unroll
    for (int o = 32; o > 0; o >>= 1) { s += __shfl_xor(s, o); q += __shfl_xor(q, o); }
    __shared__ float sm[4], qm[4];
    const int lane = tid & 63, wv = tid >> 6;
    if (lane == 0) { sm[wv] = s; qm[wv] = q; }
    __syncthreads();
    s = sm[0] + sm[1] + sm[2] + sm[3];
    q = qm[0] + qm[1] + qm[2] + qm[3];
    const float mu = s * (1.f / 512.f);
    const float ri = rsqrtf(q * (1.f / 512.f) - mu * mu + 1e-5f);
    float2 gg = ((const float2*)g)[tid];
    float2 bb = ((const float2*)b)[tid];
    float o0 = (v.x - mu) * ri * gg.x + bb.x;
    float o1 = (v.y - mu) * ri * gg.y + bb.y;
    if (OF32) ((float2*)(outf + (size_t)row * 512))[tid] = make_float2(o0, o1);
    if (OBF) {
        unsigned short* ob = outb + (size_t)row * 512 + tid * 2;
        ob[0] = f2b(o0); ob[1] = f2b(o1);
    }
}

// ---------- per-batch transpose x1 (b,l,d) f32 -> (b,d,l) bf16 ----------
__global__ __launch_bounds__(256) void trans_k(const float* __restrict__ x1,
                                               unsigned short* __restrict__ xt) {
    __shared__ float tile[32][33];
    const int b = blockIdx.z;
    const int d0 = blockIdx.x * 32, l0 = blockIdx.y * 32;
    const int c = threadIdx.x & 31, r = threadIdx.x >> 5;
    const float* src = x1 + ((size_t)b * 256 + l0) * 512 + d0;
#pragma unroll
    for (int i = 0; i < 4; i++) tile[r + i * 8][c] = src[(size_t)(r + i * 8) * 512 + c];
    __syncthreads();
    unsigned short* dst = xt + ((size_t)b * 512 + d0) * 256 + l0;
#pragma unroll
    for (int i = 0; i < 4; i++) dst[(size_t)(r + i * 8) * 256 + c] = f2b(tile[c][r + i * 8]);
}

// ---------- workspace layout (bytes) ----------
constexpr size_t OFF_WT_DIN  = 0;
constexpr size_t OFF_WT_SIN  = OFF_WT_DIN  + 2048ull * 512 * 2;
constexpr size_t OFF_WBC_D   = OFF_WT_SIN  + 2048ull * 512 * 2;
constexpr size_t OFF_WBC_S   = OFF_WBC_D   + 64ull * 1024 * 2;
constexpr size_t OFF_WT_DOUT = OFF_WBC_S   + 64ull * 1024 * 2;
constexpr size_t OFF_WT_SOUT = OFF_WT_DOUT + 512ull * 1024 * 2;
constexpr size_t OFF_WT_F1   = OFF_WT_SOUT + 512ull * 1024 * 2;
constexpr size_t OFF_WT_F2   = OFF_WT_F1   + 2048ull * 512 * 2;
constexpr size_t OFF_WEFF    = OFF_WT_F2   + 512ull * 2048 * 2;   // 1024x1024 bf16 (reused d_/s_)
constexpr size_t OFF_ACT     = OFF_WEFF + 1024ull * 1024 * 2;     // xd / xg bf16 (8192x512)
constexpr size_t OFF_UZ      = OFF_ACT  + 8192ull * 512 * 2;      // uz bf16 (8192x2048); reused FFN mid
constexpr size_t OFF_U       = OFF_UZ   + 8192ull * 2048 * 2;     // u bf16 (8192x1024); reused h bf16
constexpr size_t OFF_PROJ    = OFF_U    + 8192ull * 1024 * 2;     // BC f32 (8192x64)
constexpr size_t OFF_YG      = OFF_PROJ + 8192ull * 64 * 4;       // gated y bf16 (8192x1024)
constexpr size_t OFF_MOUT    = OFF_YG   + 8192ull * 1024 * 2;     // mamba out f32; reused as hend
constexpr size_t OFF_X1      = OFF_MOUT + 8192ull * 512 * 4;      // x1 f32
constexpr size_t OFF_X2      = OFF_X1   + 8192ull * 512 * 4;      // x2 f32
constexpr size_t OFF_X1T     = OFF_X2   + 8192ull * 512 * 4;      // x1^T bf16 (32,512,256)
constexpr size_t OFF_ADJB    = OFF_X1T  + 32ull * 512 * 256 * 2;  // adj bf16 (256x256)
constexpr size_t OFF_DT      = OFF_ADJB + 256ull * 256 * 2;       // dt f32 (8192x1024)
constexpr size_t OFF_HST     = OFF_DT   + 8192ull * 1024 * 4;     // hstart (32,8,1024,16) f32
constexpr size_t OFF_SC      = OFF_HST  + 32ull * 8 * 1024 * 16 * 4; // Sc (32,8,1024) f32

extern "C" void kernel_launch(void* const* d_in, const int* in_sizes, int n_in,
                              void* d_out, int out_size, void* d_ws, size_t ws_size,
                              hipStream_t stream) {
    (void)in_sizes; (void)n_in; (void)out_size; (void)ws_size;
    const float* x      = (const float*)d_in[0];
    const float* dinw   = (const float*)d_in[1];
    const float* dconvw = (const float*)d_in[2];
    const float* dconvb = (const float*)d_in[3];
    const float* dxproj = (const float*)d_in[4];
    const float* ddtw   = (const float*)d_in[5];
    const float* ddtb   = (const float*)d_in[6];
    const float* dAlog  = (const float*)d_in[7];
    const float* dD     = (const float*)d_in[8];
    const float* doutw  = (const float*)d_in[9];
    const float* dlng   = (const float*)d_in[10];
    const float* dlnb   = (const float*)d_in[11];
    const float* sinw   = (const float*)d_in[12];
    const float* sconvw = (const float*)d_in[13];
    const float* sconvb = (const float*)d_in[14];
    const float* sxproj = (const float*)d_in[15];
    const float* sdtw   = (const float*)d_in[16];
    const float* sdtb   = (const float*)d_in[17];
    const float* sAlog  = (const float*)d_in[18];
    const float* sD     = (const float*)d_in[19];
    const float* soutw  = (const float*)d_in[20];
    const float* slng   = (const float*)d_in[21];
    const float* slnb   = (const float*)d_in[22];
    const float* semb1  = (const float*)d_in[23];
    const float* semb2  = (const float*)d_in[24];
    const float* flng   = (const float*)d_in[25];
    const float* flnb   = (const float*)d_in[26];
    const float* fw1    = (const float*)d_in[27];
    const float* fb1    = (const float*)d_in[28];
    const float* fw2    = (const float*)d_in[29];
    const float* fb2    = (const float*)d_in[30];

    char* ws = (char*)d_ws;
    unsigned short* wtDin  = (unsigned short*)(ws + OFF_WT_DIN);
    unsigned short* wtSin  = (unsigned short*)(ws + OFF_WT_SIN);
    unsigned short* wbcD   = (unsigned short*)(ws + OFF_WBC_D);
    unsigned short* wbcS   = (unsigned short*)(ws + OFF_WBC_S);
    unsigned short* wtDout = (unsigned short*)(ws + OFF_WT_DOUT);
    unsigned short* wtSout = (unsigned short*)(ws + OFF_WT_SOUT);
    unsigned short* wtF1   = (unsigned short*)(ws + OFF_WT_F1);
    unsigned short* wtF2   = (unsigned short*)(ws + OFF_WT_F2);
    unsigned short* weff   = (unsigned short*)(ws + OFF_WEFF);
    unsigned short* actIn  = (unsigned short*)(ws + OFF_ACT);
    unsigned short* uzBuf  = (unsigned short*)(ws + OFF_UZ);
    unsigned short* uBuf   = (unsigned short*)(ws + OFF_U);
    float*          projB  = (float*)(ws + OFF_PROJ);
    unsigned short* ygBuf  = (unsigned short*)(ws + OFF_YG);
    float*          moutB  = (float*)(ws + OFF_MOUT);
    float*          hendB  = moutB;                        // reuse (dead until out-GEMM)
    float*          x1Buf  = (float*)(ws + OFF_X1);
    float*          x2Buf  = (float*)(ws + OFF_X2);
    unsigned short* x1tBuf = (unsigned short*)(ws + OFF_X1T);
    unsigned short* adjB   = (unsigned short*)(ws + OFF_ADJB);
    float*          dtBuf  = (float*)(ws + OFF_DT);
    float*          hstB   = (float*)(ws + OFF_HST);
    float*          scB    = (float*)(ws + OFF_SC);
    unsigned short* hBuf   = uBuf;    // reuse (u dead after scan)
    unsigned short* midBuf = uzBuf;   // reuse (uz dead after scan)

    float* outX   = (float*)d_out;
    float* outAdj = outX + 4194304;

    // 1) weight transposes/converts
    WtArgs wa;
    wa.m[0] = WtDesc{dinw,  wtDin,  512, 2048, 0};
    wa.m[1] = WtDesc{sinw,  wtSin,  512, 2048, 1024};
    wa.m[2] = WtDesc{doutw, wtDout, 1024, 512, 2048};
    wa.m[3] = WtDesc{soutw, wtSout, 1024, 512, 2560};
    wa.m[4] = WtDesc{fw1,   wtF1,   512, 2048, 3072};
    wa.m[5] = WtDesc{fw2,   wtF2,   2048, 512, 4096};
    wa.m[6] = WtDesc{dinw,  wtDin,  512, 2048, 0x7fffffff};
    wa.m[7] = WtDesc{dinw,  wtDin,  512, 2048, 0x7fffffff};
    wtrans_k<<<dim3(5120), dim3(256), 0, stream>>>(wa);

    compose_k<<<dim3(1088), dim3(256), 0, stream>>>(dxproj, ddtw, weff, wbcD);
    diff_k<<<dim3(16384), dim3(256), 0, stream>>>(x, actIn);
    adj_k<<<dim3(256), dim3(256), 0, stream>>>(semb1, semb2, outAdj, adjB);

    // ---- stage 1: DiffSSM mamba ----
    gemm_k<128,128,32,2,4,4, 1,0,0,0,0><<<dim3(64,16,1), dim3(256), 0, stream>>>(
        actIn, wtDin, uzBuf, nullptr, nullptr, 8192, 2048, 512, 0, 0, 0);
    conv_k<<<dim3(32768), dim3(256), 0, stream>>>(uzBuf, dconvw, dconvb, uBuf);
    gemm_k<128,128,32,2,4,4, 0,1,0,0,1><<<dim3(64,8,1), dim3(256), 0, stream>>>(
        uBuf, weff, dtBuf, ddtb, nullptr, 8192, 1024, 1024, 0, 0, 0);
    gemm_k<128,64,32,2,4,2, 0,0,0,0,0><<<dim3(64,1,1), dim3(256), 0, stream>>>(
        uBuf, wbcD, projB, nullptr, nullptr, 8192, 64, 1024, 0, 0, 0);
    compose_k<<<dim3(1088), dim3(256), 0, stream>>>(sxproj, sdtw, weff, wbcS); // weff free now
    scan1_k<<<dim3(4,8,32), dim3(256), 0, stream>>>(dtBuf, uBuf, projB, dAlog, hendB, scB);
    scan2_k<<<dim3(4,32),   dim3(256), 0, stream>>>(hendB, scB, dAlog, hstB);
    scan3_k<<<dim3(4,8,32), dim3(256), 0, stream>>>(dtBuf, uBuf, uzBuf, projB, dAlog, dD, hstB, ygBuf);
    gemm_k<128,128,32,2,4,4, 0,0,0,0,0><<<dim3(64,4,1), dim3(256), 0, stream>>>(
        ygBuf, wtDout, moutB, nullptr, nullptr, 8192, 512, 1024, 0, 0, 0);
    ln_k<1,1,0><<<dim3(8192), dim3(256), 0, stream>>>(moutB, x, dlng, dlnb, x1Buf, nullptr);

    // ---- stage 2: SpatialGraphMamba ----
    trans_k<<<dim3(16,8,32), dim3(256), 0, stream>>>(x1Buf, x1tBuf);
    gemm_k<128,128,32,2,4,4, 1,0,0,0,0><<<dim3(2,4,32), dim3(256), 0, stream>>>(
        adjB, x1tBuf, actIn, nullptr, nullptr, 256, 512, 256, 0, 131072, 131072);
    gemm_k<128,128,32,2,4,4, 1,0,0,0,0><<<dim3(64,16,1), dim3(256), 0, stream>>>(
        actIn, wtSin, uzBuf, nullptr, nullptr, 8192, 2048, 512, 0, 0, 0);
    conv_k<<<dim3(32768), dim3(256), 0, stream>>>(uzBuf, sconvw, sconvb, uBuf);
    gemm_k<128,128,32,2,4,4, 0,1,0,0,1><<<dim3(64,8,1), dim3(256), 0, stream>>>(
        uBuf, weff, dtBuf, sdtb, nullptr, 8192, 1024, 1024, 0, 0, 0);
    gemm_k<128,64,32,2,4,2, 0,0,0,0,0><<<dim3(64,1,1), dim3(256), 0, stream>>>(
        uBuf, wbcS, projB, nullptr, nullptr, 8192, 64, 1024, 0, 0, 0);
    scan1_k<<<dim3(4,8,32), dim3(256), 0, stream>>>(dtBuf, uBuf, projB, sAlog, hendB, scB);
    scan2_k<<<dim3(4,32),   dim3(256), 0, stream>>>(hendB, scB, sAlog, hstB);
    scan3_k<<<dim3(4,8,32), dim3(256), 0, stream>>>(dtBuf, uBuf, uzBuf, projB, sAlog, sD, hstB, ygBuf);
    gemm_k<128,128,32,2,4,4, 0,0,0,0,0><<<dim3(64,4,1), dim3(256), 0, stream>>>(
        ygBuf, wtSout, moutB, nullptr, nullptr, 8192, 512, 1024, 0, 0, 0);
    ln_k<1,1,0><<<dim3(8192), dim3(256), 0, stream>>>(moutB, x1Buf, slng, slnb, x2Buf, nullptr);

    // ---- stage 3: FFN ----
    ln_k<0,0,1><<<dim3(8192), dim3(256), 0, stream>>>(x2Buf, nullptr, flng, flnb, nullptr, hBuf);
    gemm_k<128,128,32,2,4,4, 1,1,1,0,0><<<dim3(64,16,1), dim3(256), 0, stream>>>(
        hBuf, wtF1, midBuf, fb1, nullptr, 8192, 2048, 512, 0, 0, 0);
    gemm_k<128,128,32,2,4,4, 0,1,0,1,0><<<dim3(64,4,1), dim3(256), 0, stream>>>(
        midBuf, wtF2, outX, fb2, x2Buf, 8192, 512, 2048, 0, 0, 0);
}

// Round 3
// 613.355 us; speedup vs baseline: 1.8191x; 1.1663x over previous
//
#include <hip/hip_runtime.h>

#define DEV __device__ __forceinline__

typedef __bf16 bf16x8 __attribute__((ext_vector_type(8)));
typedef float  f32x4  __attribute__((ext_vector_type(4)));

// ---------- helpers ----------
DEV unsigned short f2b(float f) {                 // f32 -> bf16 (RNE)
    union { float f; unsigned u; } v; v.f = f;
    unsigned r = v.u + 0x7fffu + ((v.u >> 16) & 1u);
    return (unsigned short)(r >> 16);
}
DEV float b2f(unsigned short h) {
    union { unsigned u; float f; } v; v.u = ((unsigned)h) << 16;
    return v.f;
}
DEV float sigmoidf_(float x) { return 1.f / (1.f + __expf(-x)); }
DEV float geluf_(float x) {                       // jax default: tanh approximation
    float t = 0.7978845608028654f * (x + 0.044715f * x * x * x);
    return 0.5f * x * (1.f + tanhf(t));
}
DEV float softplusf_(float x) { return x > 15.f ? x : log1pf(__expf(x)); }
DEV void gload_lds16(const void* g, void* l) {
    __builtin_amdgcn_global_load_lds((const __attribute__((address_space(1))) void*)g,
                                     (__attribute__((address_space(3))) void*)l, 16, 0, 0);
}

// ---------- problem constants ----------
// B=32 L=256 D=512 D_INNER=1024 D_STATE=16 DT_RANK=32 D_FF=2048, M = B*L = 8192
// proj layout (64 cols): [dt(32) | B(16) | C(16)]

// ---------- weight transpose+convert: W (K,N) f32 -> W^T (N,K) bf16 ----------
struct WtDesc { const float* s; unsigned short* d; int K; int N; int t0; };
struct WtArgs { WtDesc m[12]; };

__global__ __launch_bounds__(256) void wtrans_k(WtArgs a) {
    __shared__ float tile[32][33];
    int t = blockIdx.x;
    int mi = 0;
#pragma unroll
    for (int j = 1; j < 12; j++) if (t >= a.m[j].t0) mi = j;
    const float* src0 = a.m[mi].s;
    unsigned short* dst0 = a.m[mi].d;
    const int K = a.m[mi].K, N = a.m[mi].N;
    const int lt = t - a.m[mi].t0;
    const int ntk = K >> 5;
    const int kt = lt % ntk, nt = lt / ntk;
    const int c = threadIdx.x & 31, r = threadIdx.x >> 5;
    const float* src = src0 + (size_t)(kt * 32) * N + nt * 32;
#pragma unroll
    for (int i = 0; i < 4; i++) tile[r + i * 8][c] = src[(size_t)(r + i * 8) * N + c];
    __syncthreads();
    unsigned short* dst = dst0 + (size_t)(nt * 32) * K + kt * 32;
#pragma unroll
    for (int i = 0; i < 4; i++) dst[(size_t)(r + i * 8) * K + c] = f2b(tile[c][r + i * 8]);
}

// ---------- xd = causal diff of x, emitted bf16 ----------
__global__ __launch_bounds__(256) void diff_k(const float* __restrict__ x,
                                              unsigned short* __restrict__ xd) {
    size_t idx = (size_t)blockIdx.x * 256 + threadIdx.x;   // over 8192*512
    int l = (int)((idx >> 9) & 255);
    float v = x[idx];
    if (l > 0) v -= x[idx - 512];
    xd[idx] = f2b(v);
}

// ---------- adjacency: softmax(relu(e1 @ e2^T)) ----------
__global__ __launch_bounds__(256) void adj_k(const float* __restrict__ e1,
                                             const float* __restrict__ e2,
                                             float* __restrict__ adjf,
                                             unsigned short* __restrict__ adjb) {
    const int n = blockIdx.x, tid = threadIdx.x;
    __shared__ float e1s[16];
    __shared__ float redm[4], reds[4];
    if (tid < 16) e1s[tid] = e1[n * 16 + tid];
    __syncthreads();
    const float* e2r = e2 + tid * 16;
    float dot = 0.f;
#pragma unroll
    for (int k = 0; k < 16; k++) dot = fmaf(e1s[k], e2r[k], dot);
    float v = fmaxf(dot, 0.f);
    float m = v;
#pragma unroll
    for (int o = 32; o > 0; o >>= 1) m = fmaxf(m, __shfl_xor(m, o));
    const int lane = tid & 63, wv = tid >> 6;
    if (lane == 0) redm[wv] = m;
    __syncthreads();
    m = fmaxf(fmaxf(redm[0], redm[1]), fmaxf(redm[2], redm[3]));
    float e = __expf(v - m);
    float ssum = e;
#pragma unroll
    for (int o = 32; o > 0; o >>= 1) ssum += __shfl_xor(ssum, o);
    if (lane == 0) reds[wv] = ssum;
    __syncthreads();
    ssum = reds[0] + reds[1] + reds[2] + reds[3];
    float o = e / ssum;
    adjf[(size_t)n * 256 + tid] = o;
    adjb[(size_t)n * 256 + tid] = f2b(o);
}

// ---------- bf16 MFMA GEMM: C = A(M,K) @ B(K,N), B given transposed (N,K) ----------
// BK=64: XOR-swizzled LDS (source-side swizzle per global_load_lds rules);
// OBF epilogue staged through LDS for coalesced uint4 stores.
template<int BM, int BN, int BK, int WRN, int FM, int FN,
         int OBF, int HBIAS, int HGELU, int HRES, int HSP>
__global__ __launch_bounds__(256) void gemm_k(
    const unsigned short* __restrict__ A, const unsigned short* __restrict__ Bt,
    void* __restrict__ C, const float* __restrict__ bias, const float* __restrict__ res,
    int M, int N, int K, int lda, long sA, long sB, long sC) {
    constexpr int SMASK = BK / 8 - 1;       // slot mask (8-elem 16B slots per row)
    constexpr int KH    = BK / 32;          // 16x16x32 mfma steps per K-tile
    __shared__ __align__(16) unsigned short As[BM * BK];
    __shared__ __align__(16) unsigned short Bs[BN * BK];
    const int tid  = threadIdx.x;
    const int lane = tid & 63;
    const int wave = tid >> 6;
    const int wr = wave / WRN, wc = wave % WRN;
    const int bm = blockIdx.x * BM, bn = blockIdx.y * BN;
    const unsigned short* Ab = A  + (size_t)blockIdx.z * sA;
    const unsigned short* Bb = Bt + (size_t)blockIdx.z * sB;
    const int lrow  = lane & 15;
    const int klane = lane >> 4;            // 0..3 -> 8-elem slot within 32-k half

    f32x4 acc[FM][FN];
#pragma unroll
    for (int m = 0; m < FM; m++)
#pragma unroll
        for (int n = 0; n < FN; n++) {
            acc[m][n][0] = 0.f; acc[m][n][1] = 0.f; acc[m][n][2] = 0.f; acc[m][n][3] = 0.f;
        }

    constexpr int AI = (BM * BK) / 2048;
    constexpr int BI = (BN * BK) / 2048;

    for (int k0 = 0; k0 < K; k0 += BK) {
#pragma unroll
        for (int it = 0; it < AI; ++it) {
            int flat = (it * 256 + tid) * 8;
            int r = flat / BK, s = (flat % BK) >> 3;
            int c = (s ^ (r & SMASK)) * 8;            // pre-swizzled global column
            gload_lds16(Ab + (size_t)(bm + r) * lda + (k0 + c),
                        &As[(it * 256 + (tid & 192)) * 8]);
        }
#pragma unroll
        for (int it = 0; it < BI; ++it) {
            int flat = (it * 256 + tid) * 8;
            int r = flat / BK, s = (flat % BK) >> 3;
            int c = (s ^ (r & SMASK)) * 8;
            gload_lds16(Bb + (size_t)(bn + r) * K + (k0 + c),
                        &Bs[(it * 256 + (tid & 192)) * 8]);
        }
        __syncthreads();
#pragma unroll
        for (int kk = 0; kk < KH; kk++) {
            bf16x8 af[FM], bfv[FN];
#pragma unroll
            for (int m = 0; m < FM; m++) {
                int rr = wr * FM * 16 + m * 16 + lrow;
                int sl = (kk * 4 + klane) ^ (rr & SMASK);
                af[m] = *(const bf16x8*)&As[rr * BK + sl * 8];
            }
#pragma unroll
            for (int n = 0; n < FN; n++) {
                int rr = wc * FN * 16 + n * 16 + lrow;
                int sl = (kk * 4 + klane) ^ (rr & SMASK);
                bfv[n] = *(const bf16x8*)&Bs[rr * BK + sl * 8];
            }
#pragma unroll
            for (int m = 0; m < FM; m++)
#pragma unroll
                for (int n = 0; n < FN; n++)
                    acc[m][n] = __builtin_amdgcn_mfma_f32_16x16x32_bf16(af[m], bfv[n], acc[m][n], 0, 0, 0);
        }
        __syncthreads();
    }

    const int r0 = (lane >> 4) << 2;
    if (OBF) {
        // staged coalesced bf16 epilogue (reuses Bs), 32-row groups
        unsigned short* Cs = Bs;
        constexpr int PITCH = BN + 8;
        unsigned short* Cg = (unsigned short*)C;
#pragma unroll
        for (int g = 0; g < BM / 32; g++) {
            __syncthreads();
            if (wr == (g >> 1)) {
                const int mb = (g & 1) * 2;
#pragma unroll
                for (int mm = 0; mm < 2; mm++) {
#pragma unroll
                    for (int n = 0; n < FN; n++) {
                        const int cl = wc * FN * 16 + n * 16 + lrow;
                        float bv = HBIAS ? bias[bn + cl] : 0.f;
#pragma unroll
                        for (int j = 0; j < 4; j++) {
                            float v = acc[mb + mm][n][j] + bv;
                            if (HSP)   v = softplusf_(v);
                            if (HGELU) v = geluf_(v);
                            Cs[(mm * 16 + r0 + j) * PITCH + cl] = f2b(v);
                        }
                    }
                }
            }
            __syncthreads();
#pragma unroll
            for (int i = 0; i < (32 * BN) / 2048; i++) {
                int flat = (i * 256 + tid) * 8;
                int row = flat / BN, col = flat % BN;
                uint4 val = *(const uint4*)&Cs[row * PITCH + col];
                size_t oi = (size_t)blockIdx.z * sC + (size_t)(bm + g * 32 + row) * N + bn + col;
                *(uint4*)&Cg[oi] = val;
            }
        }
    } else {
#pragma unroll
        for (int n = 0; n < FN; n++) {
            const int ccol = bn + wc * FN * 16 + n * 16 + lrow;
            float bv = HBIAS ? bias[ccol] : 0.f;
#pragma unroll
            for (int m = 0; m < FM; m++) {
#pragma unroll
                for (int j = 0; j < 4; j++) {
                    const int rrow = bm + wr * FM * 16 + m * 16 + r0 + j;
                    float v = acc[m][n][j] + bv;
                    if (HSP)   v = softplusf_(v);
                    if (HGELU) v = geluf_(v);
                    if (HRES)  v += res[(size_t)rrow * N + ccol];
                    ((float*)C)[(size_t)blockIdx.z * sC + (size_t)rrow * N + ccol] = v;
                }
            }
        }
    }
}

// ---------- depthwise causal conv1d (width 4) + bias + silu, bf16 in/out ----------
__global__ __launch_bounds__(256) void conv_k(const unsigned short* __restrict__ uz,
                                              const float* __restrict__ w,
                                              const float* __restrict__ cb,
                                              unsigned short* __restrict__ u) {
    size_t idx = (size_t)blockIdx.x * 256 + threadIdx.x;   // over 8192*1024
    int d = (int)(idx & 1023);
    size_t row = idx >> 10;
    int l = (int)(row & 255);
    float acc = cb[d];
#pragma unroll
    for (int k = 0; k < 4; k++) {
        int ls = l + k - 3;
        if (ls >= 0) {
            long rr = (long)row + k - 3;
            acc = fmaf(w[d * 4 + k], b2f(uz[((size_t)rr << 11) + d]), acc);
        }
    }
    u[idx] = f2b(acc * sigmoidf_(acc));
}

// ---------- chunked selective scan (NC=8 chunks of LC=32) ----------
// pass 1: per-chunk local scan (h0=0) -> hend (b,c,d,16), Sc (b,c,d) = sum dt
__global__ __launch_bounds__(256) void scan1_k(
    const float* __restrict__ dt,              // (8192,1024) f32
    const unsigned short* __restrict__ u,      // (8192,1024) bf16
    const unsigned short* __restrict__ proj,   // (8192,64) bf16: B at 32..47
    const float* __restrict__ A_log,
    float* __restrict__ hend, float* __restrict__ Sc) {
    const int dg = blockIdx.x, c = blockIdx.y, b = blockIdx.z;
    const int d = dg * 256 + threadIdx.x;
    const size_t base = (size_t)b * 256 + c * 32;
    __shared__ float Bs[32][16];
    for (int i = threadIdx.x; i < 512; i += 256) {
        int r = i >> 4, s = i & 15;
        Bs[r][s] = b2f(proj[(base + r) * 64 + 32 + s]);
    }
    __syncthreads();
    float Aa[16];
#pragma unroll
    for (int s = 0; s < 16; s++) Aa[s] = -__expf(A_log[d * 16 + s]);
    float h[16];
#pragma unroll
    for (int s = 0; s < 16; s++) h[s] = 0.f;
    float ssum = 0.f;
    for (int l = 0; l < 32; l++) {
        size_t row = base + l;
        float dtv = dt[(row << 10) + d];
        float uu  = b2f(u[(row << 10) + d]);
        float du  = dtv * uu;
        ssum += dtv;
#pragma unroll
        for (int s = 0; s < 16; s++)
            h[s] = __expf(dtv * Aa[s]) * h[s] + du * Bs[l][s];
    }
    size_t o = (size_t)(b * 8 + c) * 1024 + d;
    Sc[o] = ssum;
#pragma unroll
    for (int s = 0; s < 16; s++) hend[o * 16 + s] = h[s];
}

// pass 2: propagate chunk-start states sequentially over the 8 chunks
__global__ __launch_bounds__(256) void scan2_k(
    const float* __restrict__ hend, const float* __restrict__ Sc,
    const float* __restrict__ A_log, float* __restrict__ hstart) {
    const int d = blockIdx.x * 256 + threadIdx.x;
    const int b = blockIdx.y;
    float Aa[16];
#pragma unroll
    for (int s = 0; s < 16; s++) Aa[s] = -__expf(A_log[d * 16 + s]);
    float h[16];
#pragma unroll
    for (int s = 0; s < 16; s++) h[s] = 0.f;
    for (int c = 0; c < 8; c++) {
        size_t o = (size_t)(b * 8 + c) * 1024 + d;
#pragma unroll
        for (int s = 0; s < 16; s++) hstart[o * 16 + s] = h[s];
        float sc = Sc[o];
#pragma unroll
        for (int s = 0; s < 16; s++)
            h[s] = __expf(sc * Aa[s]) * h[s] + hend[o * 16 + s];
    }
}

// pass 3: recompute local scans with correct h_start; fused y=h.C + u*D, z-gate
__global__ __launch_bounds__(256) void scan3_k(
    const float* __restrict__ dt,
    const unsigned short* __restrict__ u,
    const unsigned short* __restrict__ uz,     // z at col 1024+d
    const unsigned short* __restrict__ proj,   // B at 32..47, C at 48..63
    const float* __restrict__ A_log,
    const float* __restrict__ Dp,
    const float* __restrict__ hstart,
    unsigned short* __restrict__ yg) {
    const int dg = blockIdx.x, c = blockIdx.y, b = blockIdx.z;
    const int d = dg * 256 + threadIdx.x;
    const size_t base = (size_t)b * 256 + c * 32;
    __shared__ float BCs[32][32];
    for (int i = threadIdx.x; i < 1024; i += 256) {
        int r = i >> 5, s = i & 31;
        BCs[r][s] = b2f(proj[(base + r) * 64 + 32 + s]);
    }
    __syncthreads();
    float Aa[16];
#pragma unroll
    for (int s = 0; s < 16; s++) Aa[s] = -__expf(A_log[d * 16 + s]);
    const float Dd = Dp[d];
    float h[16];
    size_t ho = ((size_t)(b * 8 + c) * 1024 + d) * 16;
#pragma unroll
    for (int s = 0; s < 16; s++) h[s] = hstart[ho + s];
    for (int l = 0; l < 32; l++) {
        size_t row = base + l;
        float dtv = dt[(row << 10) + d];
        float uu  = b2f(u[(row << 10) + d]);
        float zz  = b2f(uz[(row << 11) + 1024 + d]);
        float du  = dtv * uu;
        float y = 0.f;
#pragma unroll
        for (int s = 0; s < 16; s++) {
            h[s] = __expf(dtv * Aa[s]) * h[s] + du * BCs[l][s];
            y = fmaf(h[s], BCs[l][16 + s], y);
        }
        y = fmaf(uu, Dd, y);
        yg[(row << 10) + d] = f2b(y * (zz * sigmoidf_(zz)));
    }
}

// ---------- residual-add + layernorm ----------
template<int HRES, int OF32, int OBF>
__global__ __launch_bounds__(256) void ln_k(const float* __restrict__ xin,
                                            const float* __restrict__ resin,
                                            const float* __restrict__ g,
                                            const float* __restrict__ b,
                                            float* __restrict__ outf,
                                            unsigned short* __restrict__ outb) {
    const int row = blockIdx.x, tid = threadIdx.x;
    float2 v = ((const float2*)(xin + (size_t)row * 512))[tid];
    if (HRES) {
        float2 r2 = ((const float2*)(resin + (size_t)row * 512))[tid];
        v.x += r2.x; v.y += r2.y;
    }
    float s = v.x + v.y, q = v.x * v.x + v.y * v.y;
#pragma unroll
    for (int o = 32; o > 0; o >>= 1) { s += __shfl_xor(s, o); q += __shfl_xor(q, o); }
    __shared__ float sm[4], qm[4];
    const int lane = tid & 63, wv = tid >> 6;
    if (lane == 0) { sm[wv] = s; qm[wv] = q; }
    __syncthreads();
    s = sm[0] + sm[1] + sm[2] + sm[3];
    q = qm[0] + qm[1] + qm[2] + qm[3];
    const float mu = s * (1.f / 512.f);
    const float ri = rsqrtf(q * (1.f / 512.f) - mu * mu + 1e-5f);
    float2 gg = ((const float2*)g)[tid];
    float2 bb = ((const float2*)b)[tid];
    float o0 = (v.x - mu) * ri * gg.x + bb.x;
    float o1 = (v.y - mu) * ri * gg.y + bb.y;
    if (OF32) ((float2*)(outf + (size_t)row * 512))[tid] = make_float2(o0, o1);
    if (OBF) {
        unsigned short* ob = outb + (size_t)row * 512 + tid * 2;
        ob[0] = f2b(o0); ob[1] = f2b(o1);
    }
}

// ---------- per-batch transpose x1 (b,l,d) f32 -> (b,d,l) bf16 ----------
__global__ __launch_bounds__(256) void trans_k(const float* __restrict__ x1,
                                               unsigned short* __restrict__ xt) {
    __shared__ float tile[32][33];
    const int b = blockIdx.z;
    const int d0 = blockIdx.x * 32, l0 = blockIdx.y * 32;
    const int c = threadIdx.x & 31, r = threadIdx.x >> 5;
    const float* src = x1 + ((size_t)b * 256 + l0) * 512 + d0;
#pragma unroll
    for (int i = 0; i < 4; i++) tile[r + i * 8][c] = src[(size_t)(r + i * 8) * 512 + c];
    __syncthreads();
    unsigned short* dst = xt + ((size_t)b * 512 + d0) * 256 + l0;
#pragma unroll
    for (int i = 0; i < 4; i++) dst[(size_t)(r + i * 8) * 256 + c] = f2b(tile[c][r + i * 8]);
}

// ---------- workspace layout (bytes) ----------
constexpr size_t OFF_WT_DIN  = 0;
constexpr size_t OFF_WT_SIN  = OFF_WT_DIN  + 2048ull * 512 * 2;
constexpr size_t OFF_WT_DOUT = OFF_WT_SIN  + 2048ull * 512 * 2;
constexpr size_t OFF_WT_SOUT = OFF_WT_DOUT + 512ull * 1024 * 2;
constexpr size_t OFF_WT_F1   = OFF_WT_SOUT + 512ull * 1024 * 2;
constexpr size_t OFF_WT_F2   = OFF_WT_F1   + 2048ull * 512 * 2;
constexpr size_t OFF_XPT_D   = OFF_WT_F2   + 512ull * 2048 * 2;   // xproj^T (64,1024) bf16
constexpr size_t OFF_XPT_S   = OFF_XPT_D   + 64ull * 1024 * 2;
constexpr size_t OFF_DTT_D   = OFF_XPT_S   + 64ull * 1024 * 2;    // dtw^T (1024,32) bf16
constexpr size_t OFF_DTT_S   = OFF_DTT_D   + 1024ull * 32 * 2;
constexpr size_t OFF_ACT     = OFF_DTT_S   + 1024ull * 32 * 2;    // xd / xg bf16 (8192x512)
constexpr size_t OFF_UZ      = OFF_ACT  + 8192ull * 512 * 2;      // uz bf16 (8192x2048); reused FFN mid
constexpr size_t OFF_U       = OFF_UZ   + 8192ull * 2048 * 2;     // u bf16 (8192x1024); reused h bf16
constexpr size_t OFF_PROJ    = OFF_U    + 8192ull * 1024 * 2;     // proj bf16 (8192x64)
constexpr size_t OFF_YG      = OFF_PROJ + 8192ull * 64 * 2;       // gated y bf16 (8192x1024)
constexpr size_t OFF_MOUT    = OFF_YG   + 8192ull * 1024 * 2;     // mamba out f32; reused as hend
constexpr size_t OFF_X1      = OFF_MOUT + 8192ull * 512 * 4;      // x1 f32
constexpr size_t OFF_X2      = OFF_X1   + 8192ull * 512 * 4;      // x2 f32
constexpr size_t OFF_X1T     = OFF_X2   + 8192ull * 512 * 4;      // x1^T bf16 (32,512,256)
constexpr size_t OFF_ADJB    = OFF_X1T  + 32ull * 512 * 256 * 2;  // adj bf16 (256x256)
constexpr size_t OFF_DT      = OFF_ADJB + 256ull * 256 * 2;       // dt f32 (8192x1024)
constexpr size_t OFF_HST     = OFF_DT   + 8192ull * 1024 * 4;     // hstart (32,8,1024,16) f32
constexpr size_t OFF_SC      = OFF_HST  + 32ull * 8 * 1024 * 16 * 4; // Sc (32,8,1024) f32

extern "C" void kernel_launch(void* const* d_in, const int* in_sizes, int n_in,
                              void* d_out, int out_size, void* d_ws, size_t ws_size,
                              hipStream_t stream) {
    (void)in_sizes; (void)n_in; (void)out_size; (void)ws_size;
    const float* x      = (const float*)d_in[0];
    const float* dinw   = (const float*)d_in[1];
    const float* dconvw = (const float*)d_in[2];
    const float* dconvb = (const float*)d_in[3];
    const float* dxproj = (const float*)d_in[4];
    const float* ddtw   = (const float*)d_in[5];
    const float* ddtb   = (const float*)d_in[6];
    const float* dAlog  = (const float*)d_in[7];
    const float* dD     = (const float*)d_in[8];
    const float* doutw  = (const float*)d_in[9];
    const float* dlng   = (const float*)d_in[10];
    const float* dlnb   = (const float*)d_in[11];
    const float* sinw   = (const float*)d_in[12];
    const float* sconvw = (const float*)d_in[13];
    const float* sconvb = (const float*)d_in[14];
    const float* sxproj = (const float*)d_in[15];
    const float* sdtw   = (const float*)d_in[16];
    const float* sdtb   = (const float*)d_in[17];
    const float* sAlog  = (const float*)d_in[18];
    const float* sD     = (const float*)d_in[19];
    const float* soutw  = (const float*)d_in[20];
    const float* slng   = (const float*)d_in[21];
    const float* slnb   = (const float*)d_in[22];
    const float* semb1  = (const float*)d_in[23];
    const float* semb2  = (const float*)d_in[24];
    const float* flng   = (const float*)d_in[25];
    const float* flnb   = (const float*)d_in[26];
    const float* fw1    = (const float*)d_in[27];
    const float* fb1    = (const float*)d_in[28];
    const float* fw2    = (const float*)d_in[29];
    const float* fb2    = (const float*)d_in[30];

    char* ws = (char*)d_ws;
    unsigned short* wtDin  = (unsigned short*)(ws + OFF_WT_DIN);
    unsigned short* wtSin  = (unsigned short*)(ws + OFF_WT_SIN);
    unsigned short* wtDout = (unsigned short*)(ws + OFF_WT_DOUT);
    unsigned short* wtSout = (unsigned short*)(ws + OFF_WT_SOUT);
    unsigned short* wtF1   = (unsigned short*)(ws + OFF_WT_F1);
    unsigned short* wtF2   = (unsigned short*)(ws + OFF_WT_F2);
    unsigned short* xptD   = (unsigned short*)(ws + OFF_XPT_D);
    unsigned short* xptS   = (unsigned short*)(ws + OFF_XPT_S);
    unsigned short* dttD   = (unsigned short*)(ws + OFF_DTT_D);
    unsigned short* dttS   = (unsigned short*)(ws + OFF_DTT_S);
    unsigned short* actIn  = (unsigned short*)(ws + OFF_ACT);
    unsigned short* uzBuf  = (unsigned short*)(ws + OFF_UZ);
    unsigned short* uBuf   = (unsigned short*)(ws + OFF_U);
    unsigned short* projB  = (unsigned short*)(ws + OFF_PROJ);
    unsigned short* ygBuf  = (unsigned short*)(ws + OFF_YG);
    float*          moutB  = (float*)(ws + OFF_MOUT);
    float*          hendB  = moutB;                        // reuse (dead until out-GEMM)
    float*          x1Buf  = (float*)(ws + OFF_X1);
    float*          x2Buf  = (float*)(ws + OFF_X2);
    unsigned short* x1tBuf = (unsigned short*)(ws + OFF_X1T);
    unsigned short* adjB   = (unsigned short*)(ws + OFF_ADJB);
    float*          dtBuf  = (float*)(ws + OFF_DT);
    float*          hstB   = (float*)(ws + OFF_HST);
    float*          scB    = (float*)(ws + OFF_SC);
    unsigned short* hBuf   = uBuf;    // reuse (u dead after scan)
    unsigned short* midBuf = uzBuf;   // reuse (uz dead after scan)

    float* outX   = (float*)d_out;
    float* outAdj = outX + 4194304;

    // 1) weight transposes/converts
    WtArgs wa;
    wa.m[0]  = WtDesc{dinw,   wtDin,  512,  2048, 0};
    wa.m[1]  = WtDesc{sinw,   wtSin,  512,  2048, 1024};
    wa.m[2]  = WtDesc{doutw,  wtDout, 1024, 512,  2048};
    wa.m[3]  = WtDesc{soutw,  wtSout, 1024, 512,  2560};
    wa.m[4]  = WtDesc{fw1,    wtF1,   512,  2048, 3072};
    wa.m[5]  = WtDesc{fw2,    wtF2,   2048, 512,  4096};
    wa.m[6]  = WtDesc{dxproj, xptD,   1024, 64,   5120};
    wa.m[7]  = WtDesc{sxproj, xptS,   1024, 64,   5184};
    wa.m[8]  = WtDesc{ddtw,   dttD,   32,   1024, 5248};
    wa.m[9]  = WtDesc{sdtw,   dttS,   32,   1024, 5280};
    wa.m[10] = WtDesc{dinw,   wtDin,  512,  2048, 0x7fffffff};
    wa.m[11] = WtDesc{dinw,   wtDin,  512,  2048, 0x7fffffff};
    wtrans_k<<<dim3(5312), dim3(256), 0, stream>>>(wa);

    diff_k<<<dim3(16384), dim3(256), 0, stream>>>(x, actIn);
    adj_k<<<dim3(256), dim3(256), 0, stream>>>(semb1, semb2, outAdj, adjB);

    // ---- stage 1: DiffSSM mamba ----
    gemm_k<128,128,64,2,4,4, 1,0,0,0,0><<<dim3(64,16,1), dim3(256), 0, stream>>>(
        actIn, wtDin, uzBuf, nullptr, nullptr, 8192, 2048, 512, 512, 0, 0, 0);
    conv_k<<<dim3(32768), dim3(256), 0, stream>>>(uzBuf, dconvw, dconvb, uBuf);
    gemm_k<128,64,64,2,4,2, 1,0,0,0,0><<<dim3(64,1,1), dim3(256), 0, stream>>>(
        uBuf, xptD, projB, nullptr, nullptr, 8192, 64, 1024, 1024, 0, 0, 0);
    gemm_k<128,128,32,2,4,4, 0,1,0,0,1><<<dim3(64,8,1), dim3(256), 0, stream>>>(
        projB, dttD, dtBuf, ddtb, nullptr, 8192, 1024, 32, 64, 0, 0, 0);
    scan1_k<<<dim3(4,8,32), dim3(256), 0, stream>>>(dtBuf, uBuf, projB, dAlog, hendB, scB);
    scan2_k<<<dim3(4,32),   dim3(256), 0, stream>>>(hendB, scB, dAlog, hstB);
    scan3_k<<<dim3(4,8,32), dim3(256), 0, stream>>>(dtBuf, uBuf, uzBuf, projB, dAlog, dD, hstB, ygBuf);
    gemm_k<128,128,64,2,4,4, 0,0,0,0,0><<<dim3(64,4,1), dim3(256), 0, stream>>>(
        ygBuf, wtDout, moutB, nullptr, nullptr, 8192, 512, 1024, 1024, 0, 0, 0);
    ln_k<1,1,0><<<dim3(8192), dim3(256), 0, stream>>>(moutB, x, dlng, dlnb, x1Buf, nullptr);

    // ---- stage 2: SpatialGraphMamba ----
    trans_k<<<dim3(16,8,32), dim3(256), 0, stream>>>(x1Buf, x1tBuf);
    gemm_k<128,128,64,2,4,4, 1,0,0,0,0><<<dim3(2,4,32), dim3(256), 0, stream>>>(
        adjB, x1tBuf, actIn, nullptr, nullptr, 256, 512, 256, 256, 0, 131072, 131072);
    gemm_k<128,128,64,2,4,4, 1,0,0,0,0><<<dim3(64,16,1), dim3(256), 0, stream>>>(
        actIn, wtSin, uzBuf, nullptr, nullptr, 8192, 2048, 512, 512, 0, 0, 0);
    conv_k<<<dim3(32768), dim3(256), 0, stream>>>(uzBuf, sconvw, sconvb, uBuf);
    gemm_k<128,64,64,2,4,2, 1,0,0,0,0><<<dim3(64,1,1), dim3(256), 0, stream>>>(
        uBuf, xptS, projB, nullptr, nullptr, 8192, 64, 1024, 1024, 0, 0, 0);
    gemm_k<128,128,32,2,4,4, 0,1,0,0,1><<<dim3(64,8,1), dim3(256), 0, stream>>>(
        projB, dttS, dtBuf, sdtb, nullptr, 8192, 1024, 32, 64, 0, 0, 0);
    scan1_k<<<dim3(4,8,32), dim3(256), 0, stream>>>(dtBuf, uBuf, projB, sAlog, hendB, scB);
    scan2_k<<<dim3(4,32),   dim3(256), 0, stream>>>(hendB, scB, sAlog, hstB);
    scan3_k<<<dim3(4,8,32), dim3(256), 0, stream>>>(dtBuf, uBuf, uzBuf, projB, sAlog, sD, hstB, ygBuf);
    gemm_k<128,128,64,2,4,4, 0,0,0,0,0><<<dim3(64,4,1), dim3(256), 0, stream>>>(
        ygBuf, wtSout, moutB, nullptr, nullptr, 8192, 512, 1024, 1024, 0, 0, 0);
    ln_k<1,1,0><<<dim3(8192), dim3(256), 0, stream>>>(moutB, x1Buf, slng, slnb, x2Buf, nullptr);

    // ---- stage 3: FFN ----
    ln_k<0,0,1><<<dim3(8192), dim3(256), 0, stream>>>(x2Buf, nullptr, flng, flnb, nullptr, hBuf);
    gemm_k<128,128,64,2,4,4, 1,1,1,0,0><<<dim3(64,16,1), dim3(256), 0, stream>>>(
        hBuf, wtF1, midBuf, fb1, nullptr, 8192, 2048, 512, 512, 0, 0, 0);
    gemm_k<128,128,64,2,4,4, 0,1,0,1,0><<<dim3(64,4,1), dim3(256), 0, stream>>>(
        midBuf, wtF2, outX, fb2, x2Buf, 8192, 512, 2048, 2048, 0, 0, 0);
}